// Round 3
// baseline (4508.977 us; speedup 1.0000x reference)
//
#include <hip/hip_runtime.h>

// VectorQuantizer: bf16-MFMA approximate distance pass + margin shortlist +
// exact f32 rescore + gather/losses.
// N=32768 rows, D=256, K=8192 codes.
// Correctness: shortlist margin 5e-4 >> 100*sigma of bf16 rounding error in d;
// rescore replicates R2's exact-chain d = fl(fl(a-2u)+c), lex (d,k) argmin.

#define NROWS 32768
#define NE    8192
#define DDIM  256
#define BM    128
#define CAP   32
#define MARGIN 5e-4f

typedef __attribute__((ext_vector_type(8))) short bf16x8;
typedef __attribute__((ext_vector_type(4))) float f32x4;
typedef unsigned short u16;

__device__ __forceinline__ u16 f2bf(float f) {
  unsigned x = __float_as_uint(f);
  return (u16)((x + 0x7fffu + ((x >> 16) & 1u)) >> 16);   // RNE
}

__device__ __forceinline__ void gload_lds16(const void* g, void* l) {
  __builtin_amdgcn_global_load_lds(
      (const __attribute__((address_space(1))) void*)g,
      (__attribute__((address_space(3))) void*)l, 16, 0, 0);
}

// ---------------- row norms: a[n] = sum z^2, c[k] = sum e^2 -------------
__global__ __launch_bounds__(256)
void vq_norms(const float* __restrict__ z, const float* __restrict__ emb,
              float* __restrict__ arow, float* __restrict__ cemb) {
  int gid  = blockIdx.x * 256 + threadIdx.x;
  int wid  = gid >> 6;
  int lane = threadIdx.x & 63;
  const float* src;
  float* dst;
  if (wid < NROWS) { src = z + (size_t)wid * DDIM;   dst = arow + wid; }
  else             { int r = wid - NROWS;
                     src = emb + (size_t)r * DDIM;   dst = cemb + r; }
  float4 v = *reinterpret_cast<const float4*>(src + lane * 4);
  float s = v.x * v.x + v.y * v.y;
  s += v.z * v.z;
  s += v.w * v.w;
  #pragma unroll
  for (int off = 1; off < 64; off <<= 1) s += __shfl_xor(s, off, 64);
  if (lane == 0) *dst = s;
}

// ---------------- emb f32 -> bf16, pre-swizzled (chunk c holds c^(r&7)) --
__global__ __launch_bounds__(256)
void vq_cvt(const float* __restrict__ emb, u16* __restrict__ e16) {
  int g = blockIdx.x * 256 + threadIdx.x;   // 16B-chunk id, NE*32 total
  int r = g >> 5, c = g & 31;
  int cg = c ^ (r & 7);
  const float* src = emb + (size_t)r * DDIM + cg * 8;
  float4 v0 = *reinterpret_cast<const float4*>(src);
  float4 v1 = *reinterpret_cast<const float4*>(src + 4);
  u16 o[8] = {f2bf(v0.x), f2bf(v0.y), f2bf(v0.z), f2bf(v0.w),
              f2bf(v1.x), f2bf(v1.y), f2bf(v1.z), f2bf(v1.w)};
  // 16B store
  *reinterpret_cast<bf16x8*>(e16 + (size_t)g * 8) =
      *reinterpret_cast<bf16x8*>(o);
}

// ---------------- MFMA approx pass + shortlist --------------------------
__global__ __launch_bounds__(256)
void vq_mfma(const float* __restrict__ z, const u16* __restrict__ e16,
             const float* __restrict__ arow, const float* __restrict__ cemb,
             unsigned* __restrict__ cnt, int* __restrict__ list) {
  __shared__ u16 As[BM * DDIM];   // 64KB, chunk-swizzled [row][c^(row&7)]
  __shared__ u16 Bs[128 * DDIM];  // 64KB, pre-swizzled in e16

  const int t    = threadIdx.x;
  const int R0   = blockIdx.x * BM;
  const int lane = t & 63;
  const int wid  = t >> 6;
  const int wm   = wid >> 1;      // 0..1 : row half
  const int wn   = wid & 1;       // 0..1 : cand half
  const int l15  = lane & 15;
  const int lg   = lane >> 4;     // 0..3

  // ---- stage A once: z f32 -> bf16, swizzled ----
  #pragma unroll
  for (int i = 0; i < 16; ++i) {
    int idx = i * 256 + t;        // chunk id 0..4095
    int r = idx >> 5, c = idx & 31;
    int cg = c ^ (r & 7);
    const float* src = z + (size_t)(R0 + r) * DDIM + cg * 8;
    float4 v0 = *reinterpret_cast<const float4*>(src);
    float4 v1 = *reinterpret_cast<const float4*>(src + 4);
    u16 o[8] = {f2bf(v0.x), f2bf(v0.y), f2bf(v0.z), f2bf(v0.w),
                f2bf(v1.x), f2bf(v1.y), f2bf(v1.z), f2bf(v1.w)};
    *reinterpret_cast<bf16x8*>(&As[idx * 8]) = *reinterpret_cast<bf16x8*>(o);
  }

  // ---- per-lane row constants ----
  float a_r[4][4], runmin[4][4], lanemin[4][4];
  #pragma unroll
  for (int mi = 0; mi < 4; ++mi)
    #pragma unroll
    for (int rr = 0; rr < 4; ++rr) {
      a_r[mi][rr] = arow[R0 + wm * 64 + mi * 16 + lg * 4 + rr];
      runmin[mi][rr] = 3.4e38f;
    }

  // ---- prologue: stage B chunk 0 ----
  {
    const char* src = (const char*)e16;
    #pragma unroll
    for (int i = 0; i < 16; ++i) {
      int blk = wid * 16 + i;
      gload_lds16(src + blk * 1024 + lane * 16, (char*)Bs + blk * 1024);
    }
  }
  __syncthreads();

  for (int ch = 0; ch < NE / 128; ++ch) {
    // ---- compute: D = A * B^T for this 128-cand chunk ----
    f32x4 acc[4][4];
    #pragma unroll
    for (int mi = 0; mi < 4; ++mi)
      #pragma unroll
      for (int ni = 0; ni < 4; ++ni)
        acc[mi][ni] = (f32x4){0.f, 0.f, 0.f, 0.f};

    #pragma unroll
    for (int s = 0; s < 8; ++s) {
      const int sw = ((s * 4 + lg) ^ (l15 & 7)) * 8;
      bf16x8 af[4], bf[4];
      #pragma unroll
      for (int mi = 0; mi < 4; ++mi)
        af[mi] = *reinterpret_cast<const bf16x8*>(
            &As[(wm * 64 + mi * 16 + l15) * DDIM + sw]);
      #pragma unroll
      for (int ni = 0; ni < 4; ++ni)
        bf[ni] = *reinterpret_cast<const bf16x8*>(
            &Bs[(wn * 64 + ni * 16 + l15) * DDIM + sw]);
      #pragma unroll
      for (int mi = 0; mi < 4; ++mi)
        #pragma unroll
        for (int ni = 0; ni < 4; ++ni)
          acc[mi][ni] = __builtin_amdgcn_mfma_f32_16x16x32_bf16(
              af[mi], bf[ni], acc[mi][ni], 0, 0, 0);
    }

    __syncthreads();   // all waves done reading Bs

    // ---- issue next chunk's DMA (overlaps epilogue) ----
    if (ch + 1 < NE / 128) {
      const char* src = (const char*)e16 + (size_t)(ch + 1) * 65536;
      #pragma unroll
      for (int i = 0; i < 16; ++i) {
        int blk = wid * 16 + i;
        gload_lds16(src + blk * 1024 + lane * 16, (char*)Bs + blk * 1024);
      }
    }

    // ---- epilogue: d = fl(a - 2u) + c, running min, margin appends ----
    const int C0 = ch * 128;
    float cv[4];
    #pragma unroll
    for (int ni = 0; ni < 4; ++ni)
      cv[ni] = cemb[C0 + wn * 64 + ni * 16 + l15];

    #pragma unroll
    for (int mi = 0; mi < 4; ++mi)
      #pragma unroll
      for (int rr = 0; rr < 4; ++rr) {
        float d0 = fmaf(-2.0f, acc[mi][0][rr], a_r[mi][rr]) + cv[0];
        float d1 = fmaf(-2.0f, acc[mi][1][rr], a_r[mi][rr]) + cv[1];
        float d2 = fmaf(-2.0f, acc[mi][2][rr], a_r[mi][rr]) + cv[2];
        float d3 = fmaf(-2.0f, acc[mi][3][rr], a_r[mi][rr]) + cv[3];
        float lm = fminf(fminf(d0, d1), fminf(d2, d3));
        lanemin[mi][rr] = lm;
        float gm = lm;
        gm = fminf(gm, __shfl_xor(gm, 1, 64));
        gm = fminf(gm, __shfl_xor(gm, 2, 64));
        gm = fminf(gm, __shfl_xor(gm, 4, 64));
        gm = fminf(gm, __shfl_xor(gm, 8, 64));
        runmin[mi][rr] = fminf(runmin[mi][rr], gm);
      }

    #pragma unroll
    for (int mi = 0; mi < 4; ++mi)
      #pragma unroll
      for (int rr = 0; rr < 4; ++rr) {
        float thr = runmin[mi][rr] + MARGIN;
        if (lanemin[mi][rr] <= thr) {
          // u-form test (avoids CSE with min-phase): d<=thr <=> u>=0.5(a+c-thr)
          int rowg = R0 + wm * 64 + mi * 16 + lg * 4 + rr;
          float h = 0.5f * (a_r[mi][rr] - thr);
          #pragma unroll
          for (int ni = 0; ni < 4; ++ni) {
            if (acc[mi][ni][rr] >= fmaf(0.5f, cv[ni], h)) {
              int k = C0 + wn * 64 + ni * 16 + l15;
              unsigned p = atomicAdd(&cnt[rowg], 1u);
              if (p < CAP) list[(size_t)rowg * CAP + p] = k;
            }
          }
        }
      }

    __syncthreads();   // drains vmcnt(0): next B chunk staged
  }
}

// ---------------- exact f32 rescore of shortlists -----------------------
__global__ __launch_bounds__(256)
void vq_rescore(const float* __restrict__ z, const float* __restrict__ emb,
                const float* __restrict__ arow, const float* __restrict__ cemb,
                const unsigned* __restrict__ cnt, const int* __restrict__ list,
                int* __restrict__ ws_idx) {
  const int row  = blockIdx.x * 4 + (threadIdx.x >> 6);
  const int lane = threadIdx.x & 63;
  const float a  = arow[row];
  const float4 zv = *reinterpret_cast<const float4*>(
      z + (size_t)row * DDIM + lane * 4);
  unsigned n = cnt[row];
  float bd = 3.4e38f;
  int   bk = 0;

  const bool fullscan = (n == 0 || n > CAP);
  const int  m = fullscan ? NE : (int)n;
  for (int i = 0; i < m; ++i) {
    int k = fullscan ? i : list[(size_t)row * CAP + i];
    const float4 ev = *reinterpret_cast<const float4*>(
        emb + (size_t)k * DDIM + lane * 4);
    float p = zv.x * ev.x;
    p = fmaf(zv.y, ev.y, p);
    p = fmaf(zv.z, ev.z, p);
    p = fmaf(zv.w, ev.w, p);
    #pragma unroll
    for (int off = 1; off < 64; off <<= 1) p += __shfl_xor(p, off, 64);
    float d = fmaf(-2.0f, p, a) + cemb[k];   // exact ref chain
    if (d < bd || (d == bd && k < bk)) { bd = d; bk = k; }
  }
  if (lane == 0) ws_idx[row] = bk;
}

// ---------------- gather + STE + losses ---------------------------------
__global__ __launch_bounds__(256)
void vq_gather(const float* __restrict__ z, const float* __restrict__ emb,
               const int* __restrict__ ws_idx,
               float* __restrict__ out_zq, float* __restrict__ out_idx,
               double* __restrict__ loss_accum) {
  __shared__ float part[4];
  const int t  = threadIdx.x;
  const int R0 = blockIdx.x * BM;
  float lsum = 0.0f;
  for (int rr = 0; rr < BM; ++rr) {
    const int kb = ws_idx[R0 + rr];
    const size_t gi = (size_t)(R0 + rr) * DDIM + t;
    const float zv = z[gi];
    const float qv = emb[(size_t)kb * DDIM + t];
    const float diff = qv - zv;              // z_q - z
    out_zq[gi] = zv + diff;                  // z + (z_q - z) exact chain
    lsum = fmaf(diff, diff, lsum);
  }
  #pragma unroll
  for (int off = 1; off < 64; off <<= 1) lsum += __shfl_xor(lsum, off, 64);
  if ((t & 63) == 0) part[t >> 6] = lsum;
  __syncthreads();
  if (t == 0) {
    float tot = (part[0] + part[1]) + (part[2] + part[3]);
    atomicAdd(loss_accum, (double)tot);
  }
  if (t < BM) out_idx[R0 + t] = (float)ws_idx[R0 + t];
}

// ---------------- scalar losses -----------------------------------------
__global__ void vq_finalize(const double* __restrict__ loss_accum,
                            float* __restrict__ out_losses) {
  double m = *loss_accum / (double)((size_t)NROWS * DDIM);
  out_losses[0] = (float)(0.25 * m);   // loss_commit = BETA * mse
  out_losses[1] = (float)m;            // loss_codebook
}

extern "C" void kernel_launch(void* const* d_in, const int* in_sizes, int n_in,
                              void* d_out, int out_size, void* d_ws, size_t ws_size,
                              hipStream_t stream) {
  const float* z   = (const float*)d_in[0];
  const float* emb = (const float*)d_in[1];
  float* out        = (float*)d_out;
  float* out_zq     = out;                            // [8388608]
  float* out_losses = out + (size_t)NROWS * DDIM;     // [2]
  float* out_idx    = out + (size_t)NROWS * DDIM + 2; // [32768] as f32

  // persistent ws scratch (small)
  double* loss_accum = (double*)d_ws;
  float*  arow   = (float*)((char*)d_ws + 256);
  float*  cemb   = arow + NROWS;
  int*    ws_idx = (int*)(cemb + NE);

  // large scratch carved from d_out's z_q region (overwritten by vq_gather
  // after all readers finish; rewritten every call => deterministic)
  u16*      e16  = (u16*)d_out;                              // [0, 4MB)
  int*      list = (int*)((char*)d_out + (4 << 20));         // [4MB, 8MB)
  unsigned* cnt  = (unsigned*)((char*)d_out + (8 << 20));    // [8MB, +128KB)

  hipMemsetAsync(d_ws, 0, 8, stream);
  hipMemsetAsync(cnt, 0, NROWS * sizeof(unsigned), stream);
  vq_norms<<<(NROWS + NE) / 4, 256, 0, stream>>>(z, emb, arow, cemb);
  vq_cvt<<<NE * 32 / 256, 256, 0, stream>>>(emb, e16);
  vq_mfma<<<NROWS / BM, 256, 0, stream>>>(z, e16, arow, cemb, cnt, list);
  vq_rescore<<<NROWS / 4, 256, 0, stream>>>(z, emb, arow, cemb, cnt, list, ws_idx);
  vq_gather<<<NROWS / BM, 256, 0, stream>>>(z, emb, ws_idx,
                                            out_zq, out_idx, loss_accum);
  vq_finalize<<<1, 1, 0, stream>>>(loss_accum, out_losses);
}

// Round 5
// 507.112 us; speedup vs baseline: 8.8915x; 8.8915x over previous
//
#include <hip/hip_runtime.h>

// VectorQuantizer: bf16-MFMA approximate distance pass + margin shortlist +
// exact f32 rescore + gather/losses.  N=32768 rows, D=256, K=8192 codes.
//
// R5 = R3's post-timing-PROVEN kernels with MARGIN 5e-4 -> 1e-4 only.
// R4's double-buffered/af-in-registers vq_mfma diverged on graph replay
// (race; suspects: As aliasing Bs[0] under the prologue DMA, 8-wave
// DMA-before-compute pipeline). Reverted to the R3 schedule: dedicated As,
// single B buffer, DMA issued after compute+sync (overlaps epilogue only).
// MARGIN=1e-4 was validated by R4's first call (exact idx): bound is
// 2*max|d_bf16 - d_f32| ~ 5e-5 < 1e-4. It cuts shortlist appends to ~12/row
// => CAP overflow never happens => rescore's serial fullscan tail (R3's
// 3.97ms, 88% of runtime) disappears.

#define NROWS 32768
#define NE    8192
#define DDIM  256
#define BM    128
#define CAP   32
#define MARGIN 1e-4f

typedef __attribute__((ext_vector_type(8))) short bf16x8;
typedef __attribute__((ext_vector_type(4))) float f32x4;
typedef unsigned short u16;

__device__ __forceinline__ u16 f2bf(float f) {
  unsigned x = __float_as_uint(f);
  return (u16)((x + 0x7fffu + ((x >> 16) & 1u)) >> 16);   // RNE
}

__device__ __forceinline__ void gload_lds16(const void* g, void* l) {
  __builtin_amdgcn_global_load_lds(
      (const __attribute__((address_space(1))) void*)g,
      (__attribute__((address_space(3))) void*)l, 16, 0, 0);
}

// ---------------- row norms: a[n] = sum z^2, c[k] = sum e^2 -------------
__global__ __launch_bounds__(256)
void vq_norms(const float* __restrict__ z, const float* __restrict__ emb,
              float* __restrict__ arow, float* __restrict__ cemb) {
  int gid  = blockIdx.x * 256 + threadIdx.x;
  int wid  = gid >> 6;
  int lane = threadIdx.x & 63;
  const float* src;
  float* dst;
  if (wid < NROWS) { src = z + (size_t)wid * DDIM;   dst = arow + wid; }
  else             { int r = wid - NROWS;
                     src = emb + (size_t)r * DDIM;   dst = cemb + r; }
  float4 v = *reinterpret_cast<const float4*>(src + lane * 4);
  float s = v.x * v.x + v.y * v.y;
  s += v.z * v.z;
  s += v.w * v.w;
  #pragma unroll
  for (int off = 1; off < 64; off <<= 1) s += __shfl_xor(s, off, 64);
  if (lane == 0) *dst = s;
}

// -------- emb f32 -> bf16, pre-swizzled (LDS slot c holds chunk c^(r&7)) --
__global__ __launch_bounds__(256)
void vq_cvt(const float* __restrict__ emb, u16* __restrict__ e16) {
  int g = blockIdx.x * 256 + threadIdx.x;   // 16B-chunk id, NE*32 total
  int r = g >> 5, c = g & 31;
  int cg = c ^ (r & 7);
  const float* src = emb + (size_t)r * DDIM + cg * 8;
  float4 v0 = *reinterpret_cast<const float4*>(src);
  float4 v1 = *reinterpret_cast<const float4*>(src + 4);
  u16 o[8] = {f2bf(v0.x), f2bf(v0.y), f2bf(v0.z), f2bf(v0.w),
              f2bf(v1.x), f2bf(v1.y), f2bf(v1.z), f2bf(v1.w)};
  *reinterpret_cast<bf16x8*>(e16 + (size_t)g * 8) =
      *reinterpret_cast<bf16x8*>(o);
}

// ---------------- MFMA approx pass + shortlist (R3-proven) ---------------
__global__ __launch_bounds__(256)
void vq_mfma(const float* __restrict__ z, const u16* __restrict__ e16,
             const float* __restrict__ arow, const float* __restrict__ cemb,
             unsigned* __restrict__ cnt, int* __restrict__ list) {
  __shared__ u16 As[BM * DDIM];   // 64KB, chunk-swizzled [row][c^(row&7)]
  __shared__ u16 Bs[128 * DDIM];  // 64KB, pre-swizzled in e16

  const int t    = threadIdx.x;
  const int R0   = blockIdx.x * BM;
  const int lane = t & 63;
  const int wid  = t >> 6;
  const int wm   = wid >> 1;      // 0..1 : row half
  const int wn   = wid & 1;       // 0..1 : cand half
  const int l15  = lane & 15;
  const int lg   = lane >> 4;     // 0..3

  // ---- stage A once: z f32 -> bf16, swizzled ----
  #pragma unroll
  for (int i = 0; i < 16; ++i) {
    int idx = i * 256 + t;        // chunk id 0..4095
    int r = idx >> 5, c = idx & 31;
    int cg = c ^ (r & 7);
    const float* src = z + (size_t)(R0 + r) * DDIM + cg * 8;
    float4 v0 = *reinterpret_cast<const float4*>(src);
    float4 v1 = *reinterpret_cast<const float4*>(src + 4);
    u16 o[8] = {f2bf(v0.x), f2bf(v0.y), f2bf(v0.z), f2bf(v0.w),
                f2bf(v1.x), f2bf(v1.y), f2bf(v1.z), f2bf(v1.w)};
    *reinterpret_cast<bf16x8*>(&As[idx * 8]) = *reinterpret_cast<bf16x8*>(o);
  }

  // ---- per-lane row constants ----
  float a_r[4][4], runmin[4][4], lanemin[4][4];
  #pragma unroll
  for (int mi = 0; mi < 4; ++mi)
    #pragma unroll
    for (int rr = 0; rr < 4; ++rr) {
      a_r[mi][rr] = arow[R0 + wm * 64 + mi * 16 + lg * 4 + rr];
      runmin[mi][rr] = 3.4e38f;
    }

  // ---- prologue: stage B chunk 0 ----
  {
    const char* src = (const char*)e16;
    #pragma unroll
    for (int i = 0; i < 16; ++i) {
      int blk = wid * 16 + i;
      gload_lds16(src + blk * 1024 + lane * 16, (char*)Bs + blk * 1024);
    }
  }
  __syncthreads();

  for (int ch = 0; ch < NE / 128; ++ch) {
    // ---- compute: D = A * B^T for this 128-cand chunk ----
    f32x4 acc[4][4];
    #pragma unroll
    for (int mi = 0; mi < 4; ++mi)
      #pragma unroll
      for (int ni = 0; ni < 4; ++ni)
        acc[mi][ni] = (f32x4){0.f, 0.f, 0.f, 0.f};

    #pragma unroll
    for (int s = 0; s < 8; ++s) {
      const int sw = ((s * 4 + lg) ^ (l15 & 7)) * 8;
      bf16x8 af[4], bf[4];
      #pragma unroll
      for (int mi = 0; mi < 4; ++mi)
        af[mi] = *reinterpret_cast<const bf16x8*>(
            &As[(wm * 64 + mi * 16 + l15) * DDIM + sw]);
      #pragma unroll
      for (int ni = 0; ni < 4; ++ni)
        bf[ni] = *reinterpret_cast<const bf16x8*>(
            &Bs[(wn * 64 + ni * 16 + l15) * DDIM + sw]);
      #pragma unroll
      for (int mi = 0; mi < 4; ++mi)
        #pragma unroll
        for (int ni = 0; ni < 4; ++ni)
          acc[mi][ni] = __builtin_amdgcn_mfma_f32_16x16x32_bf16(
              af[mi], bf[ni], acc[mi][ni], 0, 0, 0);
    }

    __syncthreads();   // all waves done reading Bs

    // ---- issue next chunk's DMA (overlaps epilogue) ----
    if (ch + 1 < NE / 128) {
      const char* src = (const char*)e16 + (size_t)(ch + 1) * 65536;
      #pragma unroll
      for (int i = 0; i < 16; ++i) {
        int blk = wid * 16 + i;
        gload_lds16(src + blk * 1024 + lane * 16, (char*)Bs + blk * 1024);
      }
    }

    // ---- epilogue: d = fl(a - 2u) + c, running min, margin appends ----
    const int C0 = ch * 128;
    float cv[4];
    #pragma unroll
    for (int ni = 0; ni < 4; ++ni)
      cv[ni] = cemb[C0 + wn * 64 + ni * 16 + l15];

    #pragma unroll
    for (int mi = 0; mi < 4; ++mi)
      #pragma unroll
      for (int rr = 0; rr < 4; ++rr) {
        float d0 = fmaf(-2.0f, acc[mi][0][rr], a_r[mi][rr]) + cv[0];
        float d1 = fmaf(-2.0f, acc[mi][1][rr], a_r[mi][rr]) + cv[1];
        float d2 = fmaf(-2.0f, acc[mi][2][rr], a_r[mi][rr]) + cv[2];
        float d3 = fmaf(-2.0f, acc[mi][3][rr], a_r[mi][rr]) + cv[3];
        float lm = fminf(fminf(d0, d1), fminf(d2, d3));
        lanemin[mi][rr] = lm;
        float gm = lm;
        gm = fminf(gm, __shfl_xor(gm, 1, 64));
        gm = fminf(gm, __shfl_xor(gm, 2, 64));
        gm = fminf(gm, __shfl_xor(gm, 4, 64));
        gm = fminf(gm, __shfl_xor(gm, 8, 64));
        runmin[mi][rr] = fminf(runmin[mi][rr], gm);
      }

    #pragma unroll
    for (int mi = 0; mi < 4; ++mi)
      #pragma unroll
      for (int rr = 0; rr < 4; ++rr) {
        float thr = runmin[mi][rr] + MARGIN;
        if (lanemin[mi][rr] <= thr) {
          // u-form test (avoids CSE with min-phase): d<=thr <=> u>=0.5(a+c-thr)
          int rowg = R0 + wm * 64 + mi * 16 + lg * 4 + rr;
          float h = 0.5f * (a_r[mi][rr] - thr);
          #pragma unroll
          for (int ni = 0; ni < 4; ++ni) {
            if (acc[mi][ni][rr] >= fmaf(0.5f, cv[ni], h)) {
              int k = C0 + wn * 64 + ni * 16 + l15;
              unsigned p = atomicAdd(&cnt[rowg], 1u);
              if (p < CAP) list[(size_t)rowg * CAP + p] = k;
            }
          }
        }
      }

    __syncthreads();   // drains vmcnt(0): next B chunk staged
  }
}

// ---------------- exact f32 rescore of shortlists -----------------------
__global__ __launch_bounds__(256)
void vq_rescore(const float* __restrict__ z, const float* __restrict__ emb,
                const float* __restrict__ arow, const float* __restrict__ cemb,
                const unsigned* __restrict__ cnt, const int* __restrict__ list,
                int* __restrict__ ws_idx) {
  const int row  = blockIdx.x * 4 + (threadIdx.x >> 6);
  const int lane = threadIdx.x & 63;
  const float a  = arow[row];
  const float4 zv = *reinterpret_cast<const float4*>(
      z + (size_t)row * DDIM + lane * 4);
  unsigned n = cnt[row];
  float bd = 3.4e38f;
  int   bk = 0;

  const bool fullscan = (n == 0 || n > CAP);
  const int  m = fullscan ? NE : (int)n;
  for (int i = 0; i < m; ++i) {
    int k = fullscan ? i : list[(size_t)row * CAP + i];
    const float4 ev = *reinterpret_cast<const float4*>(
        emb + (size_t)k * DDIM + lane * 4);
    float p = zv.x * ev.x;
    p = fmaf(zv.y, ev.y, p);
    p = fmaf(zv.z, ev.z, p);
    p = fmaf(zv.w, ev.w, p);
    #pragma unroll
    for (int off = 1; off < 64; off <<= 1) p += __shfl_xor(p, off, 64);
    float d = fmaf(-2.0f, p, a) + cemb[k];   // exact ref chain
    if (d < bd || (d == bd && k < bk)) { bd = d; bk = k; }
  }
  if (lane == 0) ws_idx[row] = bk;
}

// ---------------- gather + STE + losses ---------------------------------
__global__ __launch_bounds__(256)
void vq_gather(const float* __restrict__ z, const float* __restrict__ emb,
               const int* __restrict__ ws_idx,
               float* __restrict__ out_zq, float* __restrict__ out_idx,
               double* __restrict__ loss_accum) {
  __shared__ float part[4];
  const int t  = threadIdx.x;
  const int R0 = blockIdx.x * BM;
  float lsum = 0.0f;
  for (int rr = 0; rr < BM; ++rr) {
    const int kb = ws_idx[R0 + rr];
    const size_t gi = (size_t)(R0 + rr) * DDIM + t;
    const float zv = z[gi];
    const float qv = emb[(size_t)kb * DDIM + t];
    const float diff = qv - zv;              // z_q - z
    out_zq[gi] = zv + diff;                  // z + (z_q - z) exact chain
    lsum = fmaf(diff, diff, lsum);
  }
  #pragma unroll
  for (int off = 1; off < 64; off <<= 1) lsum += __shfl_xor(lsum, off, 64);
  if ((t & 63) == 0) part[t >> 6] = lsum;
  __syncthreads();
  if (t == 0) {
    float tot = (part[0] + part[1]) + (part[2] + part[3]);
    atomicAdd(loss_accum, (double)tot);
  }
  if (t < BM) out_idx[R0 + t] = (float)ws_idx[R0 + t];
}

// ---------------- scalar losses -----------------------------------------
__global__ void vq_finalize(const double* __restrict__ loss_accum,
                            float* __restrict__ out_losses) {
  double m = *loss_accum / (double)((size_t)NROWS * DDIM);
  out_losses[0] = (float)(0.25 * m);   // loss_commit = BETA * mse
  out_losses[1] = (float)m;            // loss_codebook
}

extern "C" void kernel_launch(void* const* d_in, const int* in_sizes, int n_in,
                              void* d_out, int out_size, void* d_ws, size_t ws_size,
                              hipStream_t stream) {
  const float* z   = (const float*)d_in[0];
  const float* emb = (const float*)d_in[1];
  float* out        = (float*)d_out;
  float* out_zq     = out;                            // [8388608]
  float* out_losses = out + (size_t)NROWS * DDIM;     // [2]
  float* out_idx    = out + (size_t)NROWS * DDIM + 2; // [32768] as f32

  // persistent ws scratch (small)
  double* loss_accum = (double*)d_ws;
  float*  arow   = (float*)((char*)d_ws + 256);
  float*  cemb   = arow + NROWS;
  int*    ws_idx = (int*)(cemb + NE);

  // large scratch carved from d_out's z_q region (fully rewritten each call;
  // vq_gather overwrites after all readers are done => deterministic)
  u16*      e16  = (u16*)d_out;                              // [0, 4MB)
  int*      list = (int*)((char*)d_out + (4 << 20));         // [4MB, 8MB)
  unsigned* cnt  = (unsigned*)((char*)d_out + (8 << 20));    // [8MB, +128KB)

  hipMemsetAsync(d_ws, 0, 8, stream);
  hipMemsetAsync(cnt, 0, NROWS * sizeof(unsigned), stream);
  vq_norms<<<(NROWS + NE) / 4, 256, 0, stream>>>(z, emb, arow, cemb);
  vq_cvt<<<NE * 32 / 256, 256, 0, stream>>>(emb, e16);
  vq_mfma<<<NROWS / BM, 256, 0, stream>>>(z, e16, arow, cemb, cnt, list);
  vq_rescore<<<NROWS / 4, 256, 0, stream>>>(z, emb, arow, cemb, cnt, list, ws_idx);
  vq_gather<<<NROWS / BM, 256, 0, stream>>>(z, emb, ws_idx,
                                            out_zq, out_idx, loss_accum);
  vq_finalize<<<1, 1, 0, stream>>>(loss_accum, out_losses);
}

// Round 6
// 494.165 us; speedup vs baseline: 9.1244x; 1.0262x over previous
//
#include <hip/hip_runtime.h>

// VectorQuantizer: bf16-MFMA approximate distance pass + margin shortlist +
// exact f32 rescore + gather/losses.  N=32768 rows, D=256, K=8192 codes.
//
// R6: vq_mfma restructure (R5 counters: 434us, MfmaUtil 13%, 1.68e7 bank
// conflicts, DMA serialized behind epilogue-only window):
//  - A (z) fragments loaded ONCE from global f32 -> bf16 registers. No As
//    LDS buffer at all => no LDS aliasing (R4's race suspect), half the
//    per-chunk LDS reads, no As bank conflicts.
//  - Bs double-buffered 2x64KB, DMA for ch+1 issued BEFORE compute(ch),
//    one barrier per chunk (guide's verified minimal 2-phase template).
//  - Swapped operands mfma(bf, af): lane holds 16 cands of ONE z-row =>
//    row-min = 15 fminf + 2 shuffles (vs 80 shuffles), lane-local appends.
// Epilogue append predicate = R5's verified u-form, MARGIN=1e-4 (R5-proven).

#define NROWS 32768
#define NE    8192
#define DDIM  256
#define BM    128
#define CAP   32
#define MARGIN 1e-4f
#define NCH   (NE / 128)

typedef __attribute__((ext_vector_type(8))) short bf16x8;
typedef __attribute__((ext_vector_type(4))) float f32x4;
typedef unsigned short u16;

__device__ __forceinline__ u16 f2bf(float f) {
  unsigned x = __float_as_uint(f);
  return (u16)((x + 0x7fffu + ((x >> 16) & 1u)) >> 16);   // RNE
}

__device__ __forceinline__ void gload_lds16(const void* g, void* l) {
  __builtin_amdgcn_global_load_lds(
      (const __attribute__((address_space(1))) void*)g,
      (__attribute__((address_space(3))) void*)l, 16, 0, 0);
}

// ---------------- row norms: a[n] = sum z^2, c[k] = sum e^2 -------------
__global__ __launch_bounds__(256)
void vq_norms(const float* __restrict__ z, const float* __restrict__ emb,
              float* __restrict__ arow, float* __restrict__ cemb) {
  int gid  = blockIdx.x * 256 + threadIdx.x;
  int wid  = gid >> 6;
  int lane = threadIdx.x & 63;
  const float* src;
  float* dst;
  if (wid < NROWS) { src = z + (size_t)wid * DDIM;   dst = arow + wid; }
  else             { int r = wid - NROWS;
                     src = emb + (size_t)r * DDIM;   dst = cemb + r; }
  float4 v = *reinterpret_cast<const float4*>(src + lane * 4);
  float s = v.x * v.x + v.y * v.y;
  s += v.z * v.z;
  s += v.w * v.w;
  #pragma unroll
  for (int off = 1; off < 64; off <<= 1) s += __shfl_xor(s, off, 64);
  if (lane == 0) *dst = s;
}

// -------- emb f32 -> bf16, pre-swizzled (slot c holds chunk c^(r&7)) -----
__global__ __launch_bounds__(256)
void vq_cvt(const float* __restrict__ emb, u16* __restrict__ e16) {
  int g = blockIdx.x * 256 + threadIdx.x;   // 16B-chunk id, NE*32 total
  int r = g >> 5, c = g & 31;
  int cg = c ^ (r & 7);
  const float* src = emb + (size_t)r * DDIM + cg * 8;
  float4 v0 = *reinterpret_cast<const float4*>(src);
  float4 v1 = *reinterpret_cast<const float4*>(src + 4);
  u16 o[8] = {f2bf(v0.x), f2bf(v0.y), f2bf(v0.z), f2bf(v0.w),
              f2bf(v1.x), f2bf(v1.y), f2bf(v1.z), f2bf(v1.w)};
  *reinterpret_cast<bf16x8*>(e16 + (size_t)g * 8) =
      *reinterpret_cast<bf16x8*>(o);
}

// ---------------- MFMA approx pass + shortlist --------------------------
// 4 waves: wm=wid>>1 (64-row half), wn=wid&1 (64-cand half).
// acc[zi][ci] via mfma(bf,af): D row = cand (lg*4+reg), col = z-row (l15).
__global__ __launch_bounds__(256)
void vq_mfma(const float* __restrict__ z, const u16* __restrict__ e16,
             const float* __restrict__ arow, const float* __restrict__ cemb,
             unsigned* __restrict__ cnt, int* __restrict__ list) {
  __shared__ u16 Bs[2][128 * DDIM];   // 2 x 64 KB (no A buffer)

  const int t    = threadIdx.x;
  const int R0   = blockIdx.x * BM;
  const int lane = t & 63;
  const int wid  = t >> 6;          // 0..3
  const int wm   = wid >> 1;        // 0..1 : 64-row half
  const int wn   = wid & 1;         // 0..1 : 64-cand half
  const int l15  = lane & 15;
  const int lg   = lane >> 4;       // 0..3

  // ---- A fragments: straight from global z, f32 -> bf16, in registers ----
  // af[zi][s] = z-row (R0+wm*64+zi*16+l15), global k-chunk (s*4+lg)*8..+8
  bf16x8 af[4][8];
  float  a_r[4], runmin[4];
  #pragma unroll
  for (int zi = 0; zi < 4; ++zi) {
    const int row = R0 + wm * 64 + zi * 16 + l15;
    const float* zr = z + (size_t)row * DDIM;
    #pragma unroll
    for (int s = 0; s < 8; ++s) {
      const float* src = zr + (s * 4 + lg) * 8;
      float4 v0 = *reinterpret_cast<const float4*>(src);
      float4 v1 = *reinterpret_cast<const float4*>(src + 4);
      u16 o[8] = {f2bf(v0.x), f2bf(v0.y), f2bf(v0.z), f2bf(v0.w),
                  f2bf(v1.x), f2bf(v1.y), f2bf(v1.z), f2bf(v1.w)};
      af[zi][s] = *reinterpret_cast<bf16x8*>(o);
    }
    a_r[zi] = arow[row];
    runmin[zi] = 3.4e38f;
  }

  // ---- prologue: DMA chunk 0 -> Bs[0] ----
  {
    const char* src = (const char*)e16;
    #pragma unroll
    for (int i = 0; i < 16; ++i) {
      int blk = wid * 16 + i;
      gload_lds16(src + blk * 1024 + lane * 16, (char*)&Bs[0][0] + blk * 1024);
    }
  }
  __syncthreads();   // drains prologue DMA (vmcnt 0 before barrier)

  for (int ch = 0; ch < NCH; ++ch) {
    const int buf = ch & 1;

    // ---- issue next chunk's DMA first (whole chunk to land) ----
    if (ch + 1 < NCH) {
      const char* src = (const char*)e16 + (size_t)(ch + 1) * 65536;
      char* dst = (char*)&Bs[buf ^ 1][0];
      #pragma unroll
      for (int i = 0; i < 16; ++i) {
        int blk = wid * 16 + i;
        gload_lds16(src + blk * 1024 + lane * 16, dst + blk * 1024);
      }
    }

    // ---- compute: acc[zi][ci] = mfma(B-frag, A-frag) (swapped) ----
    f32x4 acc[4][4];
    #pragma unroll
    for (int zi = 0; zi < 4; ++zi)
      #pragma unroll
      for (int ci = 0; ci < 4; ++ci)
        acc[zi][ci] = (f32x4){0.f, 0.f, 0.f, 0.f};

    const u16* Bp = &Bs[buf][0];
    #pragma unroll
    for (int s = 0; s < 8; ++s) {
      const int sw = ((s * 4 + lg) ^ (l15 & 7)) * 8;
      bf16x8 bfr[4];
      #pragma unroll
      for (int ci = 0; ci < 4; ++ci)
        bfr[ci] = *reinterpret_cast<const bf16x8*>(
            &Bp[(wn * 64 + ci * 16 + l15) * DDIM + sw]);
      #pragma unroll
      for (int ci = 0; ci < 4; ++ci)
        #pragma unroll
        for (int zi = 0; zi < 4; ++zi)
          acc[zi][ci] = __builtin_amdgcn_mfma_f32_16x16x32_bf16(
              bfr[ci], af[zi][s], acc[zi][ci], 0, 0, 0);
    }

    // ---- epilogue: lane-local row mins, 2 shuffles, u-form appends ----
    // lane's z-row (per zi) = R0 + wm*64 + zi*16 + l15
    // lane's cand (ci,r)    = C0 + wn*64 + ci*16 + lg*4 + r
    const int C0 = ch * 128;
    float4 cvv[4];
    #pragma unroll
    for (int ci = 0; ci < 4; ++ci)
      cvv[ci] = *reinterpret_cast<const float4*>(
          &cemb[C0 + wn * 64 + ci * 16 + lg * 4]);

    #pragma unroll
    for (int zi = 0; zi < 4; ++zi) {
      float lm = 3.4e38f;
      #pragma unroll
      for (int ci = 0; ci < 4; ++ci)
        #pragma unroll
        for (int r = 0; r < 4; ++r) {
          float dd = fmaf(-2.0f, acc[zi][ci][r], a_r[zi]) + cvv[ci][r];
          lm = fminf(lm, dd);
        }
      float gm = fminf(lm, __shfl_xor(lm, 16, 64));
      gm = fminf(gm, __shfl_xor(gm, 32, 64));
      runmin[zi] = fminf(runmin[zi], gm);
      float thr = runmin[zi] + MARGIN;
      if (lm <= thr) {
        // u-form test (R5-verified): d<=thr <=> u >= 0.5*(a+c-thr)
        const int rowg = R0 + wm * 64 + zi * 16 + l15;
        const float h = 0.5f * (a_r[zi] - thr);
        #pragma unroll
        for (int ci = 0; ci < 4; ++ci)
          #pragma unroll
          for (int r = 0; r < 4; ++r)
            if (acc[zi][ci][r] >= fmaf(0.5f, cvv[ci][r], h)) {
              int k = C0 + wn * 64 + ci * 16 + lg * 4 + r;
              unsigned p = atomicAdd(&cnt[rowg], 1u);
              if (p < CAP) list[(size_t)rowg * CAP + p] = k;
            }
      }
    }

    __syncthreads();   // drains this chunk's reads + next chunk's DMA
  }
}

// ---------------- exact f32 rescore of shortlists -----------------------
__global__ __launch_bounds__(256)
void vq_rescore(const float* __restrict__ z, const float* __restrict__ emb,
                const float* __restrict__ arow, const float* __restrict__ cemb,
                const unsigned* __restrict__ cnt, const int* __restrict__ list,
                int* __restrict__ ws_idx) {
  const int row  = blockIdx.x * 4 + (threadIdx.x >> 6);
  const int lane = threadIdx.x & 63;
  const float a  = arow[row];
  const float4 zv = *reinterpret_cast<const float4*>(
      z + (size_t)row * DDIM + lane * 4);
  unsigned n = cnt[row];
  float bd = 3.4e38f;
  int   bk = 0;

  const bool fullscan = (n == 0 || n > CAP);
  const int  m = fullscan ? NE : (int)n;
  for (int i = 0; i < m; ++i) {
    int k = fullscan ? i : list[(size_t)row * CAP + i];
    const float4 ev = *reinterpret_cast<const float4*>(
        emb + (size_t)k * DDIM + lane * 4);
    float p = zv.x * ev.x;
    p = fmaf(zv.y, ev.y, p);
    p = fmaf(zv.z, ev.z, p);
    p = fmaf(zv.w, ev.w, p);
    #pragma unroll
    for (int off = 1; off < 64; off <<= 1) p += __shfl_xor(p, off, 64);
    float d = fmaf(-2.0f, p, a) + cemb[k];   // exact ref chain
    if (d < bd || (d == bd && k < bk)) { bd = d; bk = k; }
  }
  if (lane == 0) ws_idx[row] = bk;
}

// ---------------- gather + STE + losses ---------------------------------
__global__ __launch_bounds__(256)
void vq_gather(const float* __restrict__ z, const float* __restrict__ emb,
               const int* __restrict__ ws_idx,
               float* __restrict__ out_zq, float* __restrict__ out_idx,
               double* __restrict__ loss_accum) {
  __shared__ float part[4];
  const int t  = threadIdx.x;
  const int R0 = blockIdx.x * BM;
  float lsum = 0.0f;
  for (int rr = 0; rr < BM; ++rr) {
    const int kb = ws_idx[R0 + rr];
    const size_t gi = (size_t)(R0 + rr) * DDIM + t;
    const float zv = z[gi];
    const float qv = emb[(size_t)kb * DDIM + t];
    const float diff = qv - zv;              // z_q - z
    out_zq[gi] = zv + diff;                  // z + (z_q - z) exact chain
    lsum = fmaf(diff, diff, lsum);
  }
  #pragma unroll
  for (int off = 1; off < 64; off <<= 1) lsum += __shfl_xor(lsum, off, 64);
  if ((t & 63) == 0) part[t >> 6] = lsum;
  __syncthreads();
  if (t == 0) {
    float tot = (part[0] + part[1]) + (part[2] + part[3]);
    atomicAdd(loss_accum, (double)tot);
  }
  if (t < BM) out_idx[R0 + t] = (float)ws_idx[R0 + t];
}

// ---------------- scalar losses -----------------------------------------
__global__ void vq_finalize(const double* __restrict__ loss_accum,
                            float* __restrict__ out_losses) {
  double m = *loss_accum / (double)((size_t)NROWS * DDIM);
  out_losses[0] = (float)(0.25 * m);   // loss_commit = BETA * mse
  out_losses[1] = (float)m;            // loss_codebook
}

extern "C" void kernel_launch(void* const* d_in, const int* in_sizes, int n_in,
                              void* d_out, int out_size, void* d_ws, size_t ws_size,
                              hipStream_t stream) {
  const float* z   = (const float*)d_in[0];
  const float* emb = (const float*)d_in[1];
  float* out        = (float*)d_out;
  float* out_zq     = out;                            // [8388608]
  float* out_losses = out + (size_t)NROWS * DDIM;     // [2]
  float* out_idx    = out + (size_t)NROWS * DDIM + 2; // [32768] as f32

  // persistent ws scratch (small)
  double* loss_accum = (double*)d_ws;
  float*  arow   = (float*)((char*)d_ws + 256);
  float*  cemb   = arow + NROWS;
  int*    ws_idx = (int*)(cemb + NE);

  // large scratch carved from d_out's z_q region (fully rewritten each call;
  // vq_gather overwrites after all readers are done => deterministic)
  u16*      e16  = (u16*)d_out;                              // [0, 4MB)
  int*      list = (int*)((char*)d_out + (4 << 20));         // [4MB, 8MB)
  unsigned* cnt  = (unsigned*)((char*)d_out + (8 << 20));    // [8MB, +128KB)

  hipMemsetAsync(d_ws, 0, 8, stream);
  hipMemsetAsync(cnt, 0, NROWS * sizeof(unsigned), stream);
  vq_norms<<<(NROWS + NE) / 4, 256, 0, stream>>>(z, emb, arow, cemb);
  vq_cvt<<<NE * 32 / 256, 256, 0, stream>>>(emb, e16);
  vq_mfma<<<NROWS / BM, 256, 0, stream>>>(z, e16, arow, cemb, cnt, list);
  vq_rescore<<<NROWS / 4, 256, 0, stream>>>(z, emb, arow, cemb, cnt, list, ws_idx);
  vq_gather<<<NROWS / BM, 256, 0, stream>>>(z, emb, ws_idx,
                                            out_zq, out_idx, loss_accum);
  vq_finalize<<<1, 1, 0, stream>>>(loss_accum, out_losses);
}

// Round 7
// 354.138 us; speedup vs baseline: 12.7323x; 1.3954x over previous
//
#include <hip/hip_runtime.h>

// VectorQuantizer: bf16-MFMA approximate distance pass + margin shortlist +
// exact f32 rescore + gather/losses.  N=32768 rows, D=256, K=8192 codes.
//
// R7: single change vs R6 — vq_mfma goes 4 -> 8 waves (512 thr), same tile,
// same 2-phase schedule. R6 post-mortem: MFMA pipe is 16.1 cyc/MFMA *per
// SIMD*; at 1 wave/SIMD all VALU/LDS/DMA/shuffle latency was serial with
// MFMA. 2 waves/SIMD lets the pipes overlap (m114). Per-wave work halves
// (wm=wid>>1: 4 row-quarters; wn=wid&1: 2 cand-halves -> append stats
// identical to R5/R6, rescore untouched). MFMA floor 55us.

#define NROWS 32768
#define NE    8192
#define DDIM  256
#define BM    128
#define CAP   32
#define MARGIN 1e-4f
#define NCH   (NE / 128)

typedef __attribute__((ext_vector_type(8))) short bf16x8;
typedef __attribute__((ext_vector_type(4))) float f32x4;
typedef unsigned short u16;

__device__ __forceinline__ u16 f2bf(float f) {
  unsigned x = __float_as_uint(f);
  return (u16)((x + 0x7fffu + ((x >> 16) & 1u)) >> 16);   // RNE
}

__device__ __forceinline__ void gload_lds16(const void* g, void* l) {
  __builtin_amdgcn_global_load_lds(
      (const __attribute__((address_space(1))) void*)g,
      (__attribute__((address_space(3))) void*)l, 16, 0, 0);
}

// ---------------- row norms: a[n] = sum z^2, c[k] = sum e^2 -------------
__global__ __launch_bounds__(256)
void vq_norms(const float* __restrict__ z, const float* __restrict__ emb,
              float* __restrict__ arow, float* __restrict__ cemb) {
  int gid  = blockIdx.x * 256 + threadIdx.x;
  int wid  = gid >> 6;
  int lane = threadIdx.x & 63;
  const float* src;
  float* dst;
  if (wid < NROWS) { src = z + (size_t)wid * DDIM;   dst = arow + wid; }
  else             { int r = wid - NROWS;
                     src = emb + (size_t)r * DDIM;   dst = cemb + r; }
  float4 v = *reinterpret_cast<const float4*>(src + lane * 4);
  float s = v.x * v.x + v.y * v.y;
  s += v.z * v.z;
  s += v.w * v.w;
  #pragma unroll
  for (int off = 1; off < 64; off <<= 1) s += __shfl_xor(s, off, 64);
  if (lane == 0) *dst = s;
}

// -------- emb f32 -> bf16, pre-swizzled (slot c holds chunk c^(r&7)) -----
__global__ __launch_bounds__(256)
void vq_cvt(const float* __restrict__ emb, u16* __restrict__ e16) {
  int g = blockIdx.x * 256 + threadIdx.x;   // 16B-chunk id, NE*32 total
  int r = g >> 5, c = g & 31;
  int cg = c ^ (r & 7);
  const float* src = emb + (size_t)r * DDIM + cg * 8;
  float4 v0 = *reinterpret_cast<const float4*>(src);
  float4 v1 = *reinterpret_cast<const float4*>(src + 4);
  u16 o[8] = {f2bf(v0.x), f2bf(v0.y), f2bf(v0.z), f2bf(v0.w),
              f2bf(v1.x), f2bf(v1.y), f2bf(v1.z), f2bf(v1.w)};
  *reinterpret_cast<bf16x8*>(e16 + (size_t)g * 8) =
      *reinterpret_cast<bf16x8*>(o);
}

// ---------------- MFMA approx pass + shortlist --------------------------
// 8 waves: wm=wid>>1 (4 row-quarters x 32), wn=wid&1 (2 cand-halves x 64).
// Swapped operands mfma(bf,af): lane holds 16 cands of ONE z-row (l15).
__global__ __launch_bounds__(512, 2)
void vq_mfma(const float* __restrict__ z, const u16* __restrict__ e16,
             const float* __restrict__ arow, const float* __restrict__ cemb,
             unsigned* __restrict__ cnt, int* __restrict__ list) {
  __shared__ u16 Bs[2][128 * DDIM];   // 2 x 64 KB (no A buffer)

  const int t    = threadIdx.x;
  const int R0   = blockIdx.x * BM;
  const int lane = t & 63;
  const int wid  = t >> 6;          // 0..7
  const int wm   = wid >> 1;        // 0..3 : 32-row quarter
  const int wn   = wid & 1;         // 0..1 : 64-cand half
  const int l15  = lane & 15;
  const int lg   = lane >> 4;       // 0..3

  // ---- A fragments: straight from global z, f32 -> bf16, in registers ----
  // af[zi][s] = z-row (R0+wm*32+zi*16+l15), global k-chunk (s*4+lg)*8..+8
  bf16x8 af[2][8];
  float  a_r[2], runmin[2];
  #pragma unroll
  for (int zi = 0; zi < 2; ++zi) {
    const int row = R0 + wm * 32 + zi * 16 + l15;
    const float* zr = z + (size_t)row * DDIM;
    #pragma unroll
    for (int s = 0; s < 8; ++s) {
      const float* src = zr + (s * 4 + lg) * 8;
      float4 v0 = *reinterpret_cast<const float4*>(src);
      float4 v1 = *reinterpret_cast<const float4*>(src + 4);
      u16 o[8] = {f2bf(v0.x), f2bf(v0.y), f2bf(v0.z), f2bf(v0.w),
                  f2bf(v1.x), f2bf(v1.y), f2bf(v1.z), f2bf(v1.w)};
      af[zi][s] = *reinterpret_cast<bf16x8*>(o);
    }
    a_r[zi] = arow[row];
    runmin[zi] = 3.4e38f;
  }

  // ---- prologue: DMA chunk 0 -> Bs[0] (64 KB = 8 waves x 8 x 1 KB) ----
  {
    const char* src = (const char*)e16;
    #pragma unroll
    for (int i = 0; i < 8; ++i) {
      int blk = wid * 8 + i;
      gload_lds16(src + blk * 1024 + lane * 16, (char*)&Bs[0][0] + blk * 1024);
    }
  }
  __syncthreads();   // drains prologue DMA (vmcnt 0 before barrier)

  for (int ch = 0; ch < NCH; ++ch) {
    const int buf = ch & 1;

    // ---- issue next chunk's DMA first (whole chunk to land) ----
    if (ch + 1 < NCH) {
      const char* src = (const char*)e16 + (size_t)(ch + 1) * 65536;
      char* dst = (char*)&Bs[buf ^ 1][0];
      #pragma unroll
      for (int i = 0; i < 8; ++i) {
        int blk = wid * 8 + i;
        gload_lds16(src + blk * 1024 + lane * 16, dst + blk * 1024);
      }
    }

    // ---- compute: acc[zi][ci] = mfma(B-frag, A-frag) (swapped) ----
    f32x4 acc[2][4];
    #pragma unroll
    for (int zi = 0; zi < 2; ++zi)
      #pragma unroll
      for (int ci = 0; ci < 4; ++ci)
        acc[zi][ci] = (f32x4){0.f, 0.f, 0.f, 0.f};

    const u16* Bp = &Bs[buf][0];
    #pragma unroll
    for (int s = 0; s < 8; ++s) {
      const int sw = ((s * 4 + lg) ^ (l15 & 7)) * 8;
      bf16x8 bfr[4];
      #pragma unroll
      for (int ci = 0; ci < 4; ++ci)
        bfr[ci] = *reinterpret_cast<const bf16x8*>(
            &Bp[(wn * 64 + ci * 16 + l15) * DDIM + sw]);
      #pragma unroll
      for (int ci = 0; ci < 4; ++ci)
        #pragma unroll
        for (int zi = 0; zi < 2; ++zi)
          acc[zi][ci] = __builtin_amdgcn_mfma_f32_16x16x32_bf16(
              bfr[ci], af[zi][s], acc[zi][ci], 0, 0, 0);
    }

    // ---- epilogue: lane-local row mins, 2 shuffles, u-form appends ----
    // lane's z-row (per zi) = R0 + wm*32 + zi*16 + l15
    // lane's cand (ci,r)    = C0 + wn*64 + ci*16 + lg*4 + r
    const int C0 = ch * 128;
    float4 cvv[4];
    #pragma unroll
    for (int ci = 0; ci < 4; ++ci)
      cvv[ci] = *reinterpret_cast<const float4*>(
          &cemb[C0 + wn * 64 + ci * 16 + lg * 4]);

    #pragma unroll
    for (int zi = 0; zi < 2; ++zi) {
      float lm = 3.4e38f;
      #pragma unroll
      for (int ci = 0; ci < 4; ++ci)
        #pragma unroll
        for (int r = 0; r < 4; ++r) {
          float dd = fmaf(-2.0f, acc[zi][ci][r], a_r[zi]) + cvv[ci][r];
          lm = fminf(lm, dd);
        }
      float gm = fminf(lm, __shfl_xor(lm, 16, 64));
      gm = fminf(gm, __shfl_xor(gm, 32, 64));
      runmin[zi] = fminf(runmin[zi], gm);
      float thr = runmin[zi] + MARGIN;
      if (lm <= thr) {
        // u-form test (R5-verified): d<=thr <=> u >= 0.5*(a+c-thr)
        const int rowg = R0 + wm * 32 + zi * 16 + l15;
        const float h = 0.5f * (a_r[zi] - thr);
        #pragma unroll
        for (int ci = 0; ci < 4; ++ci)
          #pragma unroll
          for (int r = 0; r < 4; ++r)
            if (acc[zi][ci][r] >= fmaf(0.5f, cvv[ci][r], h)) {
              int k = C0 + wn * 64 + ci * 16 + lg * 4 + r;
              unsigned p = atomicAdd(&cnt[rowg], 1u);
              if (p < CAP) list[(size_t)rowg * CAP + p] = k;
            }
      }
    }

    __syncthreads();   // drains this chunk's reads + next chunk's DMA
  }
}

// ---------------- exact f32 rescore of shortlists -----------------------
__global__ __launch_bounds__(256)
void vq_rescore(const float* __restrict__ z, const float* __restrict__ emb,
                const float* __restrict__ arow, const float* __restrict__ cemb,
                const unsigned* __restrict__ cnt, const int* __restrict__ list,
                int* __restrict__ ws_idx) {
  const int row  = blockIdx.x * 4 + (threadIdx.x >> 6);
  const int lane = threadIdx.x & 63;
  const float a  = arow[row];
  const float4 zv = *reinterpret_cast<const float4*>(
      z + (size_t)row * DDIM + lane * 4);
  unsigned n = cnt[row];
  float bd = 3.4e38f;
  int   bk = 0;

  const bool fullscan = (n == 0 || n > CAP);
  const int  m = fullscan ? NE : (int)n;
  for (int i = 0; i < m; ++i) {
    int k = fullscan ? i : list[(size_t)row * CAP + i];
    const float4 ev = *reinterpret_cast<const float4*>(
        emb + (size_t)k * DDIM + lane * 4);
    float p = zv.x * ev.x;
    p = fmaf(zv.y, ev.y, p);
    p = fmaf(zv.z, ev.z, p);
    p = fmaf(zv.w, ev.w, p);
    #pragma unroll
    for (int off = 1; off < 64; off <<= 1) p += __shfl_xor(p, off, 64);
    float d = fmaf(-2.0f, p, a) + cemb[k];   // exact ref chain
    if (d < bd || (d == bd && k < bk)) { bd = d; bk = k; }
  }
  if (lane == 0) ws_idx[row] = bk;
}

// ---------------- gather + STE + losses ---------------------------------
__global__ __launch_bounds__(256)
void vq_gather(const float* __restrict__ z, const float* __restrict__ emb,
               const int* __restrict__ ws_idx,
               float* __restrict__ out_zq, float* __restrict__ out_idx,
               double* __restrict__ loss_accum) {
  __shared__ float part[4];
  const int t  = threadIdx.x;
  const int R0 = blockIdx.x * BM;
  float lsum = 0.0f;
  for (int rr = 0; rr < BM; ++rr) {
    const int kb = ws_idx[R0 + rr];
    const size_t gi = (size_t)(R0 + rr) * DDIM + t;
    const float zv = z[gi];
    const float qv = emb[(size_t)kb * DDIM + t];
    const float diff = qv - zv;              // z_q - z
    out_zq[gi] = zv + diff;                  // z + (z_q - z) exact chain
    lsum = fmaf(diff, diff, lsum);
  }
  #pragma unroll
  for (int off = 1; off < 64; off <<= 1) lsum += __shfl_xor(lsum, off, 64);
  if ((t & 63) == 0) part[t >> 6] = lsum;
  __syncthreads();
  if (t == 0) {
    float tot = (part[0] + part[1]) + (part[2] + part[3]);
    atomicAdd(loss_accum, (double)tot);
  }
  if (t < BM) out_idx[R0 + t] = (float)ws_idx[R0 + t];
}

// ---------------- scalar losses -----------------------------------------
__global__ void vq_finalize(const double* __restrict__ loss_accum,
                            float* __restrict__ out_losses) {
  double m = *loss_accum / (double)((size_t)NROWS * DDIM);
  out_losses[0] = (float)(0.25 * m);   // loss_commit = BETA * mse
  out_losses[1] = (float)m;            // loss_codebook
}

extern "C" void kernel_launch(void* const* d_in, const int* in_sizes, int n_in,
                              void* d_out, int out_size, void* d_ws, size_t ws_size,
                              hipStream_t stream) {
  const float* z   = (const float*)d_in[0];
  const float* emb = (const float*)d_in[1];
  float* out        = (float*)d_out;
  float* out_zq     = out;                            // [8388608]
  float* out_losses = out + (size_t)NROWS * DDIM;     // [2]
  float* out_idx    = out + (size_t)NROWS * DDIM + 2; // [32768] as f32

  // persistent ws scratch (small)
  double* loss_accum = (double*)d_ws;
  float*  arow   = (float*)((char*)d_ws + 256);
  float*  cemb   = arow + NROWS;
  int*    ws_idx = (int*)(cemb + NE);

  // large scratch carved from d_out's z_q region (fully rewritten each call;
  // vq_gather overwrites after all readers are done => deterministic)
  u16*      e16  = (u16*)d_out;                              // [0, 4MB)
  int*      list = (int*)((char*)d_out + (4 << 20));         // [4MB, 8MB)
  unsigned* cnt  = (unsigned*)((char*)d_out + (8 << 20));    // [8MB, +128KB)

  hipMemsetAsync(d_ws, 0, 8, stream);
  hipMemsetAsync(cnt, 0, NROWS * sizeof(unsigned), stream);
  vq_norms<<<(NROWS + NE) / 4, 256, 0, stream>>>(z, emb, arow, cemb);
  vq_cvt<<<NE * 32 / 256, 256, 0, stream>>>(emb, e16);
  vq_mfma<<<NROWS / BM, 512, 0, stream>>>(z, e16, arow, cemb, cnt, list);
  vq_rescore<<<NROWS / 4, 256, 0, stream>>>(z, emb, arow, cemb, cnt, list, ws_idx);
  vq_gather<<<NROWS / BM, 256, 0, stream>>>(z, emb, ws_idx,
                                            out_zq, out_idx, loss_accum);
  vq_finalize<<<1, 1, 0, stream>>>(loss_accum, out_losses);
}

// Round 8
// 350.199 us; speedup vs baseline: 12.8755x; 1.0112x over previous
//
#include <hip/hip_runtime.h>

// VectorQuantizer: bf16-MFMA approximate distance pass + margin shortlist +
// exact f32 rescore + gather/losses.  N=32768 rows, D=256, K=8192 codes.
//
// R8: occupancy 2->4 waves/SIMD. BM 128->64, B-chunk 128->64 cands:
// grid 512 blocks, LDS 2x32KB=64KB => 2 blocks/CU; cross-block overlap
// hides barrier drains + epilogue dependency chains (R7: half the chunk
// wall time was unaccounted latency stall at 2 waves/SIMD). cvv loads
// hoisted to chunk start (L2 latency hidden under MFMA loop). Same
// R6/R7-proven 2-phase schedule, same MARGIN/append/rescore numerics.

#define NROWS 32768
#define NE    8192
#define DDIM  256
#define BM    64
#define CAP   32
#define MARGIN 1e-4f
#define NCH   (NE / 64)    // 128 chunks of 64 candidates

typedef __attribute__((ext_vector_type(8))) short bf16x8;
typedef __attribute__((ext_vector_type(4))) float f32x4;
typedef unsigned short u16;

__device__ __forceinline__ u16 f2bf(float f) {
  unsigned x = __float_as_uint(f);
  return (u16)((x + 0x7fffu + ((x >> 16) & 1u)) >> 16);   // RNE
}

__device__ __forceinline__ void gload_lds16(const void* g, void* l) {
  __builtin_amdgcn_global_load_lds(
      (const __attribute__((address_space(1))) void*)g,
      (__attribute__((address_space(3))) void*)l, 16, 0, 0);
}

// ---------------- row norms: a[n] = sum z^2, c[k] = sum e^2 -------------
__global__ __launch_bounds__(256)
void vq_norms(const float* __restrict__ z, const float* __restrict__ emb,
              float* __restrict__ arow, float* __restrict__ cemb) {
  int gid  = blockIdx.x * 256 + threadIdx.x;
  int wid  = gid >> 6;
  int lane = threadIdx.x & 63;
  const float* src;
  float* dst;
  if (wid < NROWS) { src = z + (size_t)wid * DDIM;   dst = arow + wid; }
  else             { int r = wid - NROWS;
                     src = emb + (size_t)r * DDIM;   dst = cemb + r; }
  float4 v = *reinterpret_cast<const float4*>(src + lane * 4);
  float s = v.x * v.x + v.y * v.y;
  s += v.z * v.z;
  s += v.w * v.w;
  #pragma unroll
  for (int off = 1; off < 64; off <<= 1) s += __shfl_xor(s, off, 64);
  if (lane == 0) *dst = s;
}

// -------- emb f32 -> bf16, pre-swizzled (slot c holds chunk c^(r&7)) -----
__global__ __launch_bounds__(256)
void vq_cvt(const float* __restrict__ emb, u16* __restrict__ e16) {
  int g = blockIdx.x * 256 + threadIdx.x;   // 16B-chunk id, NE*32 total
  int r = g >> 5, c = g & 31;
  int cg = c ^ (r & 7);
  const float* src = emb + (size_t)r * DDIM + cg * 8;
  float4 v0 = *reinterpret_cast<const float4*>(src);
  float4 v1 = *reinterpret_cast<const float4*>(src + 4);
  u16 o[8] = {f2bf(v0.x), f2bf(v0.y), f2bf(v0.z), f2bf(v0.w),
              f2bf(v1.x), f2bf(v1.y), f2bf(v1.z), f2bf(v1.w)};
  *reinterpret_cast<bf16x8*>(e16 + (size_t)g * 8) =
      *reinterpret_cast<bf16x8*>(o);
}

// ---------------- MFMA approx pass + shortlist --------------------------
// 8 waves: wm=wid>>1 (4 x 16-row group), wn=wid&1 (2 x 32-cand half).
// Swapped operands mfma(bf,af): lane holds 8 cands of ONE z-row (l15).
__global__ __launch_bounds__(512, 4)
void vq_mfma(const float* __restrict__ z, const u16* __restrict__ e16,
             const float* __restrict__ arow, const float* __restrict__ cemb,
             unsigned* __restrict__ cnt, int* __restrict__ list) {
  __shared__ u16 Bs[2][64 * DDIM];   // 2 x 32 KB

  const int t    = threadIdx.x;
  const int R0   = blockIdx.x * BM;
  const int lane = t & 63;
  const int wid  = t >> 6;          // 0..7
  const int wm   = wid >> 1;        // 0..3 : 16-row group
  const int wn   = wid & 1;         // 0..1 : 32-cand half
  const int l15  = lane & 15;
  const int lg   = lane >> 4;       // 0..3

  // ---- A fragments: straight from global z, f32 -> bf16, in registers ----
  // af[s] = z-row (R0+wm*16+l15), global k-chunk (s*4+lg)*8..+8
  bf16x8 af[8];
  const int row = R0 + wm * 16 + l15;
  {
    const float* zr = z + (size_t)row * DDIM;
    #pragma unroll
    for (int s = 0; s < 8; ++s) {
      const float* src = zr + (s * 4 + lg) * 8;
      float4 v0 = *reinterpret_cast<const float4*>(src);
      float4 v1 = *reinterpret_cast<const float4*>(src + 4);
      u16 o[8] = {f2bf(v0.x), f2bf(v0.y), f2bf(v0.z), f2bf(v0.w),
                  f2bf(v1.x), f2bf(v1.y), f2bf(v1.z), f2bf(v1.w)};
      af[s] = *reinterpret_cast<bf16x8*>(o);
    }
  }
  const float a_r = arow[row];
  float runmin = 3.4e38f;

  // ---- prologue: DMA chunk 0 -> Bs[0] (32 KB = 8 waves x 4 x 1 KB) ----
  {
    const char* src = (const char*)e16;
    #pragma unroll
    for (int i = 0; i < 4; ++i) {
      int blk = wid * 4 + i;
      gload_lds16(src + blk * 1024 + lane * 16, (char*)&Bs[0][0] + blk * 1024);
    }
  }
  __syncthreads();   // drains prologue DMA

  for (int ch = 0; ch < NCH; ++ch) {
    const int buf = ch & 1;
    const int C0  = ch * 64;

    // ---- issue next chunk's DMA first (whole chunk to land) ----
    if (ch + 1 < NCH) {
      const char* src = (const char*)e16 + (size_t)(ch + 1) * 32768;
      char* dst = (char*)&Bs[buf ^ 1][0];
      #pragma unroll
      for (int i = 0; i < 4; ++i) {
        int blk = wid * 4 + i;
        gload_lds16(src + blk * 1024 + lane * 16, dst + blk * 1024);
      }
    }

    // ---- hoisted epilogue constants (L2 latency hides under MFMAs) ----
    float4 cvv[2];
    #pragma unroll
    for (int ci = 0; ci < 2; ++ci)
      cvv[ci] = *reinterpret_cast<const float4*>(
          &cemb[C0 + wn * 32 + ci * 16 + lg * 4]);

    // ---- compute: acc[ci] = mfma(B-frag, A-frag) (swapped) ----
    f32x4 acc[2];
    acc[0] = (f32x4){0.f, 0.f, 0.f, 0.f};
    acc[1] = (f32x4){0.f, 0.f, 0.f, 0.f};

    const u16* Bp = &Bs[buf][0];
    #pragma unroll
    for (int s = 0; s < 8; ++s) {
      const int sw = ((s * 4 + lg) ^ (l15 & 7)) * 8;
      bf16x8 bfr[2];
      #pragma unroll
      for (int ci = 0; ci < 2; ++ci)
        bfr[ci] = *reinterpret_cast<const bf16x8*>(
            &Bp[(wn * 32 + ci * 16 + l15) * DDIM + sw]);
      #pragma unroll
      for (int ci = 0; ci < 2; ++ci)
        acc[ci] = __builtin_amdgcn_mfma_f32_16x16x32_bf16(
            bfr[ci], af[s], acc[ci], 0, 0, 0);
    }

    // ---- epilogue: lane-local row min, 2 shuffles, u-form appends ----
    // lane's z-row = row; lane's cand (ci,r) = C0 + wn*32 + ci*16 + lg*4 + r
    float lm = 3.4e38f;
    #pragma unroll
    for (int ci = 0; ci < 2; ++ci)
      #pragma unroll
      for (int r = 0; r < 4; ++r) {
        float dd = fmaf(-2.0f, acc[ci][r], a_r) + cvv[ci][r];
        lm = fminf(lm, dd);
      }
    float gm = fminf(lm, __shfl_xor(lm, 16, 64));
    gm = fminf(gm, __shfl_xor(gm, 32, 64));
    runmin = fminf(runmin, gm);
    float thr = runmin + MARGIN;
    if (lm <= thr) {
      // u-form test (R5-verified): d<=thr <=> u >= 0.5*(a+c-thr)
      const float h = 0.5f * (a_r - thr);
      #pragma unroll
      for (int ci = 0; ci < 2; ++ci)
        #pragma unroll
        for (int r = 0; r < 4; ++r)
          if (acc[ci][r] >= fmaf(0.5f, cvv[ci][r], h)) {
            int k = C0 + wn * 32 + ci * 16 + lg * 4 + r;
            unsigned p = atomicAdd(&cnt[row], 1u);
            if (p < CAP) list[(size_t)row * CAP + p] = k;
          }
    }

    __syncthreads();   // drains this chunk's reads + next chunk's DMA
  }
}

// ---------------- exact f32 rescore of shortlists -----------------------
__global__ __launch_bounds__(256)
void vq_rescore(const float* __restrict__ z, const float* __restrict__ emb,
                const float* __restrict__ arow, const float* __restrict__ cemb,
                const unsigned* __restrict__ cnt, const int* __restrict__ list,
                int* __restrict__ ws_idx) {
  const int row  = blockIdx.x * 4 + (threadIdx.x >> 6);
  const int lane = threadIdx.x & 63;
  const float a  = arow[row];
  const float4 zv = *reinterpret_cast<const float4*>(
      z + (size_t)row * DDIM + lane * 4);
  unsigned n = cnt[row];
  float bd = 3.4e38f;
  int   bk = 0;

  const bool fullscan = (n == 0 || n > CAP);
  const int  m = fullscan ? NE : (int)n;
  for (int i = 0; i < m; ++i) {
    int k = fullscan ? i : list[(size_t)row * CAP + i];
    const float4 ev = *reinterpret_cast<const float4*>(
        emb + (size_t)k * DDIM + lane * 4);
    float p = zv.x * ev.x;
    p = fmaf(zv.y, ev.y, p);
    p = fmaf(zv.z, ev.z, p);
    p = fmaf(zv.w, ev.w, p);
    #pragma unroll
    for (int off = 1; off < 64; off <<= 1) p += __shfl_xor(p, off, 64);
    float d = fmaf(-2.0f, p, a) + cemb[k];   // exact ref chain
    if (d < bd || (d == bd && k < bk)) { bd = d; bk = k; }
  }
  if (lane == 0) ws_idx[row] = bk;
}

// ---------------- gather + STE + losses ---------------------------------
__global__ __launch_bounds__(256)
void vq_gather(const float* __restrict__ z, const float* __restrict__ emb,
               const int* __restrict__ ws_idx,
               float* __restrict__ out_zq, float* __restrict__ out_idx,
               double* __restrict__ loss_accum) {
  __shared__ float part[4];
  const int t  = threadIdx.x;
  const int R0 = blockIdx.x * 128;
  float lsum = 0.0f;
  for (int rr = 0; rr < 128; ++rr) {
    const int kb = ws_idx[R0 + rr];
    const size_t gi = (size_t)(R0 + rr) * DDIM + t;
    const float zv = z[gi];
    const float qv = emb[(size_t)kb * DDIM + t];
    const float diff = qv - zv;              // z_q - z
    out_zq[gi] = zv + diff;                  // z + (z_q - z) exact chain
    lsum = fmaf(diff, diff, lsum);
  }
  #pragma unroll
  for (int off = 1; off < 64; off <<= 1) lsum += __shfl_xor(lsum, off, 64);
  if ((t & 63) == 0) part[t >> 6] = lsum;
  __syncthreads();
  if (t == 0) {
    float tot = (part[0] + part[1]) + (part[2] + part[3]);
    atomicAdd(loss_accum, (double)tot);
  }
  if (t < 128) out_idx[R0 + t] = (float)ws_idx[R0 + t];
}

// ---------------- scalar losses -----------------------------------------
__global__ void vq_finalize(const double* __restrict__ loss_accum,
                            float* __restrict__ out_losses) {
  double m = *loss_accum / (double)((size_t)NROWS * DDIM);
  out_losses[0] = (float)(0.25 * m);   // loss_commit = BETA * mse
  out_losses[1] = (float)m;            // loss_codebook
}

extern "C" void kernel_launch(void* const* d_in, const int* in_sizes, int n_in,
                              void* d_out, int out_size, void* d_ws, size_t ws_size,
                              hipStream_t stream) {
  const float* z   = (const float*)d_in[0];
  const float* emb = (const float*)d_in[1];
  float* out        = (float*)d_out;
  float* out_zq     = out;                            // [8388608]
  float* out_losses = out + (size_t)NROWS * DDIM;     // [2]
  float* out_idx    = out + (size_t)NROWS * DDIM + 2; // [32768] as f32

  // persistent ws scratch (small)
  double* loss_accum = (double*)d_ws;
  float*  arow   = (float*)((char*)d_ws + 256);
  float*  cemb   = arow + NROWS;
  int*    ws_idx = (int*)(cemb + NE);

  // large scratch carved from d_out's z_q region (fully rewritten each call;
  // vq_gather overwrites after all readers are done => deterministic)
  u16*      e16  = (u16*)d_out;                              // [0, 4MB)
  int*      list = (int*)((char*)d_out + (4 << 20));         // [4MB, 8MB)
  unsigned* cnt  = (unsigned*)((char*)d_out + (8 << 20));    // [8MB, +128KB)

  hipMemsetAsync(d_ws, 0, 8, stream);
  hipMemsetAsync(cnt, 0, NROWS * sizeof(unsigned), stream);
  vq_norms<<<(NROWS + NE) / 4, 256, 0, stream>>>(z, emb, arow, cemb);
  vq_cvt<<<NE * 32 / 256, 256, 0, stream>>>(emb, e16);
  vq_mfma<<<NROWS / BM, 512, 0, stream>>>(z, e16, arow, cemb, cnt, list);
  vq_rescore<<<NROWS / 4, 256, 0, stream>>>(z, emb, arow, cemb, cnt, list, ws_idx);
  vq_gather<<<NROWS / 128, 256, 0, stream>>>(z, emb, ws_idx,
                                             out_zq, out_idx, loss_accum);
  vq_finalize<<<1, 1, 0, stream>>>(loss_accum, out_losses);
}